// Round 1
// baseline (1087.718 us; speedup 1.0000x reference)
//
#include <hip/hip_runtime.h>
#include <stdint.h>

#define HID 64
#define INDIM 128
// JAX RNG flavor: 1 = jax_threefry_partitionable (default in modern JAX), 0 = original
#define JAX_PARTITIONABLE 1

__host__ __device__ __forceinline__ void tf2x32(uint32_t k0, uint32_t k1,
                                                uint32_t x0, uint32_t x1,
                                                uint32_t& o0, uint32_t& o1) {
  uint32_t ks2 = k0 ^ k1 ^ 0x1BD11BDAu;
#define ROTL(v, r) (((v) << (r)) | ((v) >> (32 - (r))))
#define RND(r) { x0 += x1; x1 = ROTL(x1, r); x1 ^= x0; }
  x0 += k0; x1 += k1;
  RND(13) RND(15) RND(26) RND(6)
  x0 += k1; x1 += ks2 + 1u;
  RND(17) RND(29) RND(16) RND(24)
  x0 += ks2; x1 += k0 + 2u;
  RND(13) RND(15) RND(26) RND(6)
  x0 += k0; x1 += k1 + 3u;
  RND(17) RND(29) RND(16) RND(24)
  x0 += k1; x1 += ks2 + 4u;
  RND(13) RND(15) RND(26) RND(6)
  x0 += ks2; x1 += k0 + 5u;
  o0 = x0; o1 = x1;
#undef RND
#undef ROTL
}

__device__ __forceinline__ float tf_uniform(uint32_t ka, uint32_t kb, uint32_t j, uint32_t S) {
  uint32_t o0, o1, bits;
#if JAX_PARTITIONABLE
  tf2x32(ka, kb, 0u, j, o0, o1);
  bits = o0 ^ o1;
#else
  uint32_t half = S >> 1;
  if (j < half) { tf2x32(ka, kb, j, j + half, o0, o1); bits = o0; }
  else          { tf2x32(ka, kb, j - half, j, o0, o1); bits = o1; }
#endif
  uint32_t f = (bits >> 9) | 0x3f800000u;
  return __uint_as_float(f) - 1.0f;
}

__global__ __launch_bounds__(256) void init_k(int* deg, float* colsum, int n) {
  int i = blockIdx.x * 256 + threadIdx.x;
  if (i < n) deg[i] = 1;           // self-loop
  if (i < HID) colsum[i] = 0.f;
}

__global__ __launch_bounds__(256) void deg_k(const int* __restrict__ dst, int* deg, int E) {
  int e = blockIdx.x * 256 + threadIdx.x;
  if (e < E) atomicAdd(&deg[dst[e]], 1);
}

__global__ __launch_bounds__(256) void norm_k(const int* __restrict__ deg, float* norm, int n) {
  int i = blockIdx.x * 256 + threadIdx.x;
  if (i < n) norm[i] = rsqrtf((float)deg[i]);
}

// h0[i][l] = norm[i] * (feat[i] . w1[:,l])
__global__ __launch_bounds__(256) void gemm1(const float* __restrict__ feat,
                                             const float* __restrict__ w1,
                                             const float* __restrict__ norm,
                                             float* __restrict__ h0, int n) {
  __shared__ float w1s[INDIM * HID];   // 32 KB
  __shared__ float rows[4][INDIM];
  int t = threadIdx.x;
  for (int i = t; i < INDIM * HID; i += 256) w1s[i] = w1[i];
  int node0 = blockIdx.x * 4;
  for (int i = t; i < 4 * INDIM; i += 256) {
    int r = i >> 7, c = i & 127;
    int node = node0 + r;
    rows[r][c] = (node < n) ? feat[(size_t)node * INDIM + c] : 0.f;
  }
  __syncthreads();
  int w = t >> 6, l = t & 63;
  int node = node0 + w;
  if (node < n) {
    float acc = 0.f;
#pragma unroll
    for (int k = 0; k < INDIM; k++) acc += rows[w][k] * w1s[k * HID + l];
    h0[(size_t)node * HID + l] = acc * norm[node];
  }
}

// agg[dst[e]] += hsrc[src[e]]  (agg pre-initialized with self-loop term)
__global__ __launch_bounds__(256) void scatter_k(const float* __restrict__ hsrc,
                                                 float* __restrict__ agg,
                                                 const int* __restrict__ src,
                                                 const int* __restrict__ dst, int E) {
  long long tid = (long long)blockIdx.x * 256 + threadIdx.x;
  int e = (int)(tid >> 6);
  if (e >= E) return;
  int d = (int)(tid & 63);
  int s = src[e], dd = dst[e];
  atomicAdd(&agg[(size_t)dd * HID + d], hsrc[(size_t)s * HID + d]);
}

// t = norm * dropout(relu(agg1 * norm))    (pre-scale for layer-2 GCN)
__global__ __launch_bounds__(256) void drop1_k(const float* __restrict__ agg1,
                                               const float* __restrict__ norm,
                                               float* __restrict__ tout, int n,
                                               uint32_t ka, uint32_t kb) {
  int j = blockIdx.x * 256 + threadIdx.x;
  if (j >= n * HID) return;
  int node = j >> 6;
  float nm = norm[node];
  float v = fmaxf(agg1[j] * nm, 0.f);
  float u = tf_uniform(ka, kb, (uint32_t)j, (uint32_t)(n * HID));
  v = (u < 0.5f) ? v * 2.f : 0.f;
  tout[j] = v * nm;
}

// h2 = dropout(relu((agg2 @ w2) * norm))
__global__ __launch_bounds__(256) void gemm2(const float* __restrict__ agg2,
                                             const float* __restrict__ w2,
                                             const float* __restrict__ norm,
                                             float* __restrict__ h2, int n,
                                             uint32_t ka, uint32_t kb) {
  __shared__ float w2s[HID * HID];     // 16 KB
  __shared__ float rows[4][HID];
  int t = threadIdx.x;
  for (int i = t; i < HID * HID; i += 256) w2s[i] = w2[i];
  int node0 = blockIdx.x * 4;
  for (int i = t; i < 4 * HID; i += 256) {
    int r = i >> 6, c = i & 63;
    int node = node0 + r;
    rows[r][c] = (node < n) ? agg2[(size_t)node * HID + c] : 0.f;
  }
  __syncthreads();
  int w = t >> 6, l = t & 63;
  int node = node0 + w;
  if (node < n) {
    float acc = 0.f;
#pragma unroll
    for (int k = 0; k < HID; k++) acc += rows[w][k] * w2s[k * HID + l];
    acc = fmaxf(acc * norm[node], 0.f);
    uint32_t j = (uint32_t)(node * HID + l);
    float u = tf_uniform(ka, kb, j, (uint32_t)(n * HID));
    acc = (u < 0.5f) ? acc * 2.f : 0.f;
    h2[(size_t)node * HID + l] = acc;
  }
}

// column sums of h2 (for the conv-output mean)
__global__ __launch_bounds__(256) void colsum_k(const float* __restrict__ h2,
                                                float* __restrict__ colsum, int n) {
  int t = threadIdx.x;
  int col = t & 63;
  float s = 0.f;
  for (int r = blockIdx.x * 4 + (t >> 6); r < n; r += gridDim.x * 4)
    s += h2[(size_t)r * HID + col];
  __shared__ float red[4][HID];
  red[t >> 6][col] = s;
  __syncthreads();
  if (t < HID) {
    float v = red[0][t] + red[1][t] + red[2][t] + red[3][t];
    atomicAdd(&colsum[t], v);
  }
}

// conv(2,1,3) + bias, radius vs column mean, clip
__global__ __launch_bounds__(128) void final_k(const float* __restrict__ h2,
                                               const float* __restrict__ colsum,
                                               const float* __restrict__ conv_w,
                                               const float* __restrict__ conv_b,
                                               const float* __restrict__ ref_radius,
                                               float* __restrict__ out, int n) {
  __shared__ float rows[128 * 67];   // 67 pad: (67*l+k)%32 -> 2-way max (free)
  __shared__ float omean[124];
  __shared__ float cm[HID];
  int t = threadIdx.x;
  int node0 = blockIdx.x * 128;
  if (t < HID) cm[t] = colsum[t] * (1.0f / (float)n);
  for (int idx = t; idx < 128 * HID; idx += 128) {
    int r = idx >> 6, c = idx & 63;
    int node = node0 + r;
    rows[r * 67 + c] = (node < n) ? h2[(size_t)node * HID + c] : 0.f;
  }
  __syncthreads();
  if (t < 124) {
    int o = t / 62, i = t % 62;
    omean[t] = conv_b[o] + conv_w[o * 3] * cm[i] + conv_w[o * 3 + 1] * cm[i + 1] +
               conv_w[o * 3 + 2] * cm[i + 2];
  }
  __syncthreads();
  int node = node0 + t;
  if (node < n) {
    float r0[HID];
#pragma unroll
    for (int k = 0; k < HID; k++) r0[k] = rows[t * 67 + k];
    float w00 = conv_w[0], w01 = conv_w[1], w02 = conv_w[2];
    float w10 = conv_w[3], w11 = conv_w[4], w12 = conv_w[5];
    float b0 = conv_b[0], b1 = conv_b[1];
    float acc = 0.f;
#pragma unroll
    for (int i = 0; i < 62; i++) {
      float y0 = b0 + w00 * r0[i] + w01 * r0[i + 1] + w02 * r0[i + 2];
      float d0 = y0 - omean[i] + 1e-6f;
      acc += d0 * d0;
      float y1 = b1 + w10 * r0[i] + w11 * r0[i + 1] + w12 * r0[i + 2];
      float d1 = y1 - omean[62 + i] + 1e-6f;
      acc += d1 * d1;
    }
    float radius = sqrtf(acc);
    float dis = fminf(fmaxf(radius - ref_radius[0], 1e-4f), 1.f - 1e-4f);
    out[node] = dis;
  }
  if (blockIdx.x == 0 && t == 0) out[n] = ref_radius[0];
}

extern "C" void kernel_launch(void* const* d_in, const int* in_sizes, int n_in,
                              void* d_out, int out_size, void* d_ws, size_t ws_size,
                              hipStream_t stream) {
  const float* feat = (const float*)d_in[0];
  const float* w1 = (const float*)d_in[1];
  const float* w2 = (const float*)d_in[2];
  const float* conv_w = (const float*)d_in[3];
  const float* conv_b = (const float*)d_in[4];
  const float* ref_radius = (const float*)d_in[5];
  const int* src = (const int*)d_in[6];
  const int* dst = (const int*)d_in[7];
  int n = in_sizes[0] / INDIM;
  int E = in_sizes[6];
  float* out = (float*)d_out;

  char* p = (char*)d_ws;
  auto carve = [&](size_t bytes) { void* r = (void*)p; p += (bytes + 255) & ~(size_t)255; return r; };
  int* deg = (int*)carve((size_t)n * 4);
  float* norm = (float*)carve((size_t)n * 4);
  float* colsum = (float*)carve(HID * 4);
  float* B1 = (float*)carve((size_t)n * HID * 4);
  float* B2 = (float*)carve((size_t)n * HID * 4);

  // JAX PRNG: key(42) -> raw (0,42); split per partitionable flag
  uint32_t k1a, k1b, k2a, k2b;
#if JAX_PARTITIONABLE
  tf2x32(0u, 42u, 0u, 0u, k1a, k1b);
  tf2x32(0u, 42u, 0u, 1u, k2a, k2b);
#else
  { uint32_t a0, b0v, a1, b1v;
    tf2x32(0u, 42u, 0u, 2u, a0, b0v);
    tf2x32(0u, 42u, 1u, 3u, a1, b1v);
    k1a = a0; k1b = a1; k2a = b0v; k2b = b1v; }
#endif

  size_t hbytes = (size_t)n * HID * 4;
  int nb256 = (n + 255) / 256;
  int eb256 = (E + 255) / 256;
  long long sth = (long long)E * HID;
  int sblocks = (int)((sth + 255) / 256);

  init_k<<<nb256, 256, 0, stream>>>(deg, colsum, n);
  deg_k<<<eb256, 256, 0, stream>>>(dst, deg, E);
  norm_k<<<nb256, 256, 0, stream>>>(deg, norm, n);
  gemm1<<<(n + 3) / 4, 256, 0, stream>>>(feat, w1, norm, B1, n);
  hipMemcpyAsync(B2, B1, hbytes, hipMemcpyDeviceToDevice, stream);   // self-loop init
  scatter_k<<<sblocks, 256, 0, stream>>>(B1, B2, src, dst, E);
  drop1_k<<<(n * HID + 255) / 256, 256, 0, stream>>>(B2, norm, B1, n, k1a, k1b);
  hipMemcpyAsync(B2, B1, hbytes, hipMemcpyDeviceToDevice, stream);   // self-loop init
  scatter_k<<<sblocks, 256, 0, stream>>>(B1, B2, src, dst, E);
  gemm2<<<(n + 3) / 4, 256, 0, stream>>>(B2, w2, norm, B1, n, k2a, k2b);
  colsum_k<<<256, 256, 0, stream>>>(B1, colsum, n);
  final_k<<<(n + 127) / 128, 128, 0, stream>>>(B1, colsum, conv_w, conv_b, ref_radius, out, n);
}

// Round 2
// 690.111 us; speedup vs baseline: 1.5761x; 1.5761x over previous
//
#include <hip/hip_runtime.h>
#include <stdint.h>

#define HID 64
#define INDIM 128
#define JAX_PARTITIONABLE 1

__host__ __device__ __forceinline__ void tf2x32(uint32_t k0, uint32_t k1,
                                                uint32_t x0, uint32_t x1,
                                                uint32_t& o0, uint32_t& o1) {
  uint32_t ks2 = k0 ^ k1 ^ 0x1BD11BDAu;
#define ROTL(v, r) (((v) << (r)) | ((v) >> (32 - (r))))
#define RND(r) { x0 += x1; x1 = ROTL(x1, r); x1 ^= x0; }
  x0 += k0; x1 += k1;
  RND(13) RND(15) RND(26) RND(6)
  x0 += k1; x1 += ks2 + 1u;
  RND(17) RND(29) RND(16) RND(24)
  x0 += ks2; x1 += k0 + 2u;
  RND(13) RND(15) RND(26) RND(6)
  x0 += k0; x1 += k1 + 3u;
  RND(17) RND(29) RND(16) RND(24)
  x0 += k1; x1 += ks2 + 4u;
  RND(13) RND(15) RND(26) RND(6)
  x0 += ks2; x1 += k0 + 5u;
  o0 = x0; o1 = x1;
#undef RND
#undef ROTL
}

__device__ __forceinline__ float tf_uniform(uint32_t ka, uint32_t kb, uint32_t j) {
  uint32_t o0, o1;
  tf2x32(ka, kb, 0u, j, o0, o1);
  uint32_t bits = o0 ^ o1;
  uint32_t f = (bits >> 9) | 0x3f800000u;
  return __uint_as_float(f) - 1.0f;
}

__global__ __launch_bounds__(256) void zero_k(int* cnt, float* colsum, int n) {
  int i = blockIdx.x * 256 + threadIdx.x;
  if (i < n) cnt[i] = 0;
  if (i < HID) colsum[i] = 0.f;
}

__global__ __launch_bounds__(256) void cnt_k(const int* __restrict__ dst, int* cnt, int E) {
  int e = blockIdx.x * 256 + threadIdx.x;
  if (e < E) atomicAdd(&cnt[dst[e]], 1);
}

__global__ __launch_bounds__(256) void norm_k(const int* __restrict__ cnt, float* norm, int n) {
  int i = blockIdx.x * 256 + threadIdx.x;
  if (i < n) norm[i] = rsqrtf((float)(cnt[i] + 1));
}

// --- exclusive scan of cnt[0..n) into rowstart, 3-phase ---
__global__ __launch_bounds__(256) void scan1_k(const int* __restrict__ cnt,
                                               int* __restrict__ rowstart,
                                               int* __restrict__ bsum, int n) {
  __shared__ int s[256];
  int t = threadIdx.x;
  int i = blockIdx.x * 256 + t;
  int v = (i < n) ? cnt[i] : 0;
  s[t] = v;
  __syncthreads();
  for (int off = 1; off < 256; off <<= 1) {
    int x = (t >= off) ? s[t - off] : 0;
    __syncthreads();
    s[t] += x;
    __syncthreads();
  }
  if (i < n) rowstart[i] = s[t] - v;      // exclusive within block
  if (t == 255) bsum[blockIdx.x] = s[255];
}

__global__ __launch_bounds__(512) void scan2_k(int* __restrict__ bsum, int B) {
  __shared__ int s[512];
  int t = threadIdx.x;
  int v = (t < B) ? bsum[t] : 0;
  s[t] = v;
  __syncthreads();
  for (int off = 1; off < 512; off <<= 1) {
    int x = (t >= off) ? s[t - off] : 0;
    __syncthreads();
    s[t] += x;
    __syncthreads();
  }
  if (t < B) bsum[t] = s[t] - v;          // exclusive
}

__global__ __launch_bounds__(256) void scan3_k(int* __restrict__ rowstart,
                                               const int* __restrict__ bsum,
                                               int n, int E) {
  int t = threadIdx.x;
  int i = blockIdx.x * 256 + t;
  if (i < n) rowstart[i] += bsum[blockIdx.x];
  if (i == 0) rowstart[n] = E;
}

__global__ __launch_bounds__(256) void fill_k(const int* __restrict__ src,
                                              const int* __restrict__ dst,
                                              int* __restrict__ cursor,
                                              int* __restrict__ csr, int E) {
  int e = blockIdx.x * 256 + threadIdx.x;
  if (e >= E) return;
  int d = dst[e];
  int pos = atomicAdd(&cursor[d], 1);
  csr[pos] = src[e];
}

// h0[i][l] = norm[i] * (feat[i] . w1[:,l])
__global__ __launch_bounds__(256) void gemm1(const float* __restrict__ feat,
                                             const float* __restrict__ w1,
                                             const float* __restrict__ norm,
                                             float* __restrict__ h0, int n) {
  __shared__ float w1s[INDIM * HID];   // 32 KB
  __shared__ float rows[4][INDIM];
  int t = threadIdx.x;
  for (int i = t; i < INDIM * HID; i += 256) w1s[i] = w1[i];
  int node0 = blockIdx.x * 4;
  for (int i = t; i < 4 * INDIM; i += 256) {
    int r = i >> 7, c = i & 127;
    int node = node0 + r;
    rows[r][c] = (node < n) ? feat[(size_t)node * INDIM + c] : 0.f;
  }
  __syncthreads();
  int w = t >> 6, l = t & 63;
  int node = node0 + w;
  if (node < n) {
    float acc = 0.f;
#pragma unroll
    for (int k = 0; k < INDIM; k++) acc += rows[w][k] * w1s[k * HID + l];
    h0[(size_t)node * HID + l] = acc * norm[node];
  }
}

// wave-per-node gather: acc = h[d] + sum_{s in csr row} h[s]; optional fused
// relu/dropout/prescale epilogue (layer 1) or raw agg output (layer 2)
template <bool DROP>
__global__ __launch_bounds__(256) void gather_k(const float* __restrict__ h,
                                                float* __restrict__ outp,
                                                const int* __restrict__ rowstart,
                                                const int* __restrict__ csr,
                                                const float* __restrict__ norm,
                                                int n, uint32_t ka, uint32_t kb) {
  int d = (int)((blockIdx.x * 256 + threadIdx.x) >> 6);
  int lane = threadIdx.x & 63;
  if (d >= n) return;
  float acc = h[(size_t)d * HID + lane];          // self loop
  int r0 = rowstart[d], r1 = rowstart[d + 1];
  for (int base = r0; base < r1; base += 64) {
    int m = r1 - base; if (m > 64) m = 64;
    int idx = (base + lane < r1) ? csr[base + lane] : 0;
    for (int j = 0; j < m; j++) {
      int s = __shfl(idx, j);
      acc += h[(size_t)s * HID + lane];
    }
  }
  if (DROP) {
    float nm = norm[d];
    float v = fmaxf(acc * nm, 0.f);
    uint32_t jj = (uint32_t)d * (uint32_t)HID + (uint32_t)lane;
    float u = tf_uniform(ka, kb, jj);
    v = (u < 0.5f) ? v * 2.f : 0.f;
    outp[(size_t)d * HID + lane] = v * nm;        // pre-scale for layer 2
  } else {
    outp[(size_t)d * HID + lane] = acc;
  }
}

// h2 = dropout(relu((agg2 @ w2) * norm))
__global__ __launch_bounds__(256) void gemm2(const float* __restrict__ agg2,
                                             const float* __restrict__ w2,
                                             const float* __restrict__ norm,
                                             float* __restrict__ h2, int n,
                                             uint32_t ka, uint32_t kb) {
  __shared__ float w2s[HID * HID];     // 16 KB
  __shared__ float rows[4][HID];
  int t = threadIdx.x;
  for (int i = t; i < HID * HID; i += 256) w2s[i] = w2[i];
  int node0 = blockIdx.x * 4;
  for (int i = t; i < 4 * HID; i += 256) {
    int r = i >> 6, c = i & 63;
    int node = node0 + r;
    rows[r][c] = (node < n) ? agg2[(size_t)node * HID + c] : 0.f;
  }
  __syncthreads();
  int w = t >> 6, l = t & 63;
  int node = node0 + w;
  if (node < n) {
    float acc = 0.f;
#pragma unroll
    for (int k = 0; k < HID; k++) acc += rows[w][k] * w2s[k * HID + l];
    acc = fmaxf(acc * norm[node], 0.f);
    uint32_t j = (uint32_t)(node * HID + l);
    float u = tf_uniform(ka, kb, j);
    acc = (u < 0.5f) ? acc * 2.f : 0.f;
    h2[(size_t)node * HID + l] = acc;
  }
}

__global__ __launch_bounds__(256) void colsum_k(const float* __restrict__ h2,
                                                float* __restrict__ colsum, int n) {
  int t = threadIdx.x;
  int col = t & 63;
  float s = 0.f;
  for (int r = blockIdx.x * 4 + (t >> 6); r < n; r += gridDim.x * 4)
    s += h2[(size_t)r * HID + col];
  __shared__ float red[4][HID];
  red[t >> 6][col] = s;
  __syncthreads();
  if (t < HID) {
    float v = red[0][t] + red[1][t] + red[2][t] + red[3][t];
    atomicAdd(&colsum[t], v);
  }
}

__global__ __launch_bounds__(128) void final_k(const float* __restrict__ h2,
                                               const float* __restrict__ colsum,
                                               const float* __restrict__ conv_w,
                                               const float* __restrict__ conv_b,
                                               const float* __restrict__ ref_radius,
                                               float* __restrict__ out, int n) {
  __shared__ float rows[128 * 67];
  __shared__ float omean[124];
  __shared__ float cm[HID];
  int t = threadIdx.x;
  int node0 = blockIdx.x * 128;
  if (t < HID) cm[t] = colsum[t] * (1.0f / (float)n);
  for (int idx = t; idx < 128 * HID; idx += 128) {
    int r = idx >> 6, c = idx & 63;
    int node = node0 + r;
    rows[r * 67 + c] = (node < n) ? h2[(size_t)node * HID + c] : 0.f;
  }
  __syncthreads();
  if (t < 124) {
    int o = t / 62, i = t % 62;
    omean[t] = conv_b[o] + conv_w[o * 3] * cm[i] + conv_w[o * 3 + 1] * cm[i + 1] +
               conv_w[o * 3 + 2] * cm[i + 2];
  }
  __syncthreads();
  int node = node0 + t;
  if (node < n) {
    float r0[HID];
#pragma unroll
    for (int k = 0; k < HID; k++) r0[k] = rows[t * 67 + k];
    float w00 = conv_w[0], w01 = conv_w[1], w02 = conv_w[2];
    float w10 = conv_w[3], w11 = conv_w[4], w12 = conv_w[5];
    float b0 = conv_b[0], b1 = conv_b[1];
    float acc = 0.f;
#pragma unroll
    for (int i = 0; i < 62; i++) {
      float y0 = b0 + w00 * r0[i] + w01 * r0[i + 1] + w02 * r0[i + 2];
      float d0 = y0 - omean[i] + 1e-6f;
      acc += d0 * d0;
      float y1 = b1 + w10 * r0[i] + w11 * r0[i + 1] + w12 * r0[i + 2];
      float d1 = y1 - omean[62 + i] + 1e-6f;
      acc += d1 * d1;
    }
    float radius = sqrtf(acc);
    float dis = fminf(fmaxf(radius - ref_radius[0], 1e-4f), 1.f - 1e-4f);
    out[node] = dis;
  }
  if (blockIdx.x == 0 && t == 0) out[n] = ref_radius[0];
}

extern "C" void kernel_launch(void* const* d_in, const int* in_sizes, int n_in,
                              void* d_out, int out_size, void* d_ws, size_t ws_size,
                              hipStream_t stream) {
  const float* feat = (const float*)d_in[0];
  const float* w1 = (const float*)d_in[1];
  const float* w2 = (const float*)d_in[2];
  const float* conv_w = (const float*)d_in[3];
  const float* conv_b = (const float*)d_in[4];
  const float* ref_radius = (const float*)d_in[5];
  const int* src = (const int*)d_in[6];
  const int* dst = (const int*)d_in[7];
  int n = in_sizes[0] / INDIM;
  int E = in_sizes[6];
  float* out = (float*)d_out;

  char* p = (char*)d_ws;
  auto carve = [&](size_t bytes) { void* r = (void*)p; p += (bytes + 255) & ~(size_t)255; return r; };
  int* cnt = (int*)carve((size_t)n * 4);
  float* norm = (float*)carve((size_t)n * 4);
  float* colsum = (float*)carve(HID * 4);
  int* rowstart = (int*)carve(((size_t)n + 1) * 4);
  int* cursor = (int*)carve((size_t)n * 4);
  int* bsum = (int*)carve(512 * 4);
  int* csr = (int*)carve((size_t)E * 4);
  float* B1 = (float*)carve((size_t)n * HID * 4);
  float* B2 = (float*)carve((size_t)n * HID * 4);

  uint32_t k1a, k1b, k2a, k2b;
  tf2x32(0u, 42u, 0u, 0u, k1a, k1b);
  tf2x32(0u, 42u, 0u, 1u, k2a, k2b);

  int nb256 = (n + 255) / 256;
  int eb256 = (E + 255) / 256;
  int B = nb256;   // scan blocks (n=100000 -> 391, fits in 512-wide scan2)

  zero_k<<<nb256, 256, 0, stream>>>(cnt, colsum, n);
  cnt_k<<<eb256, 256, 0, stream>>>(dst, cnt, E);
  norm_k<<<nb256, 256, 0, stream>>>(cnt, norm, n);
  scan1_k<<<B, 256, 0, stream>>>(cnt, rowstart, bsum, n);
  scan2_k<<<1, 512, 0, stream>>>(bsum, B);
  scan3_k<<<B, 256, 0, stream>>>(rowstart, bsum, n, E);
  hipMemcpyAsync(cursor, rowstart, (size_t)n * 4, hipMemcpyDeviceToDevice, stream);
  fill_k<<<eb256, 256, 0, stream>>>(src, dst, cursor, csr, E);

  gemm1<<<(n + 3) / 4, 256, 0, stream>>>(feat, w1, norm, B1, n);
  gather_k<true><<<(n + 3) / 4, 256, 0, stream>>>(B1, B2, rowstart, csr, norm, n, k1a, k1b);
  gather_k<false><<<(n + 3) / 4, 256, 0, stream>>>(B2, B1, rowstart, csr, norm, n, 0u, 0u);
  gemm2<<<(n + 3) / 4, 256, 0, stream>>>(B1, w2, norm, B2, n, k2a, k2b);
  colsum_k<<<256, 256, 0, stream>>>(B2, colsum, n);
  final_k<<<(n + 127) / 128, 128, 0, stream>>>(B2, colsum, conv_w, conv_b, ref_radius, out, n);
}